// Round 22
// baseline (290.884 us; speedup 1.0000x reference)
//
#include <hip/hip_runtime.h>
#include <cstdint>
#include <cstddef>

#define N_IN  700
#define N_INP 704
#define N_HID 512
#define N_OUT 20
#define BB    256
#define TT    100
#define NK    (BB*TT)
#define NCH   8

__device__ __constant__ const float TAU   = 0.6f;
__device__ __constant__ const float TAU_O = 0.6f;
__device__ __constant__ const float THR   = 0.6f;
__device__ __constant__ const float GAM   = 0.3f;

typedef float f32x4 __attribute__((ext_vector_type(4)));
typedef __bf16 bf16x8 __attribute__((ext_vector_type(8)));

__device__ __forceinline__ unsigned short f2bf_rne(float f) {
  uint32_t b = __builtin_bit_cast(uint32_t, f);
  uint32_t r = (b + 0x7FFFu + ((b >> 16) & 1u)) >> 16;
  return (unsigned short)r;
}

// ---------------- merged prep: wsplit(hi only) + transposes + sums + zero-init ----------------
// NOTE: summation order of Srow/SOs is spike-determining — keep serial order exactly.
__global__ void k_prep_all(const float* __restrict__ W1, const float* __restrict__ Wr,
                           const float* __restrict__ Wo,
                           unsigned short* __restrict__ WH,
                           float* __restrict__ WRT, float* __restrict__ WoT,
                           float* __restrict__ Srow, float* __restrict__ SOs,
                           float* __restrict__ drvb, unsigned char* __restrict__ hzf) {
  const int g = blockIdx.x*256 + threadIdx.x;
  if (g < N_HID*88) {
    int r = g / 88, c = g - (g/88)*88;
    int ib = c*8;
    unsigned short h[8];
    #pragma unroll
    for (int j = 0; j < 8; ++j) {
      int i = ib + j;
      float v = (i < N_IN) ? W1[r*N_IN + i] : 0.f;
      h[j] = f2bf_rne(v);
    }
    uint4 hv = make_uint4((uint32_t)h[0] | ((uint32_t)h[1]<<16), (uint32_t)h[2] | ((uint32_t)h[3]<<16),
                          (uint32_t)h[4] | ((uint32_t)h[5]<<16), (uint32_t)h[6] | ((uint32_t)h[7]<<16));
    *(uint4*)(WH + (size_t)r*N_INP + ib) = hv;
  }
  if (g < N_HID*N_HID) {
    int j = g >> 9, r = g & 511;
    WRT[g] = Wr[r*N_HID + j];
  }
  if (g < N_HID*N_OUT) {
    int r = g / N_OUT, o = g - r*N_OUT;
    WoT[g] = Wo[o*N_HID + r];
  }
  if (g < N_HID) {
    float s = 0.f;
    for (int j = 0; j < N_HID; ++j) s += Wr[g*N_HID + j];
    Srow[g] = s;
  } else if (g < N_HID + N_OUT) {
    int o = g - N_HID;
    float s = 0.f;
    for (int r = 0; r < N_HID; ++r) s += Wo[o*N_HID + r];
    SOs[o] = s;
  }
  if (g < NK) hzf[g] = 0;
  if (g < NK*N_OUT) drvb[g] = 0.f;
}

// ---------------- phase A: INL = X @ WH^T, bf16 MFMA, 128x128 tiles, BK=64 ----------------
// BK=64 halves the per-K-iteration barrier count (22 -> 11 iters); k-ascending MFMA chain
// per output element is preserved -> bit-identical INL vs r21.
__global__ __launch_bounds__(256) void k_gemm(const float* __restrict__ x,
                                              const unsigned short* __restrict__ WH,
                                              float* __restrict__ INL) {
  __shared__ __align__(16) unsigned short sA [128*64];   // 16 KB
  __shared__ __align__(16) unsigned short sBh[128*64];   // 16 KB
  const int tid = threadIdx.x, lane = tid & 63, w = tid >> 6;
  const int k0 = blockIdx.x * 128;
  const int c0 = blockIdx.y * 128;
  const int wr = w >> 1, wc = w & 1;
  const int fr = lane & 15, fk = lane >> 4;

  const int a_r = tid >> 1;          // 0..127
  const int a_cb = (tid & 1) * 32;   // 0 or 32
  const int b_r = tid >> 1;
  const int b_cb = (tid & 1) * 32;

  const float* xr = x + (size_t)(k0 + a_r) * N_IN;
  const unsigned short* gh = WH + (size_t)(c0 + b_r) * N_INP;

  f32x4 acc[4][4];
  #pragma unroll
  for (int m = 0; m < 4; ++m)
    #pragma unroll
    for (int n = 0; n < 4; ++n)
      acc[m][n] = (f32x4){0.f, 0.f, 0.f, 0.f};

  for (int s = 0; s < N_INP/64; ++s) {
    const int i0 = s * 64;
    const int col0 = i0 + a_cb;
    float av[32];
    if (col0 + 32 <= N_IN) {
      #pragma unroll
      for (int q = 0; q < 8; ++q) {
        const float4 t = *(const float4*)(xr + col0 + 4*q);
        av[4*q+0]=t.x; av[4*q+1]=t.y; av[4*q+2]=t.z; av[4*q+3]=t.w;
      }
    } else {
      #pragma unroll
      for (int j = 0; j < 32; ++j) av[j] = (col0 + j < N_IN) ? xr[col0 + j] : 0.f;
    }
    uint32_t us[16];
    #pragma unroll
    for (int p = 0; p < 16; ++p) {
      uint32_t lo = __builtin_bit_cast(uint32_t, av[2*p])   >> 16;   // x in {0,1}: trunc exact
      uint32_t hi = __builtin_bit_cast(uint32_t, av[2*p+1]) & 0xFFFF0000u;
      us[p] = hi | lo;
    }
    #pragma unroll
    for (int q = 0; q < 4; ++q)
      *(uint4*)&sA[a_r*64 + a_cb + 8*q] = make_uint4(us[4*q], us[4*q+1], us[4*q+2], us[4*q+3]);
    #pragma unroll
    for (int q = 0; q < 4; ++q)
      *(uint4*)&sBh[b_r*64 + b_cb + 8*q] = *(const uint4*)(gh + i0 + b_cb + 8*q);
    __syncthreads();

    #pragma unroll
    for (int ko = 0; ko < 2; ++ko) {
      bf16x8 a[4], bh[4];
      #pragma unroll
      for (int m = 0; m < 4; ++m)
        a[m] = *(const bf16x8*)&sA[(wr*64 + m*16 + fr)*64 + ko*32 + fk*8];
      #pragma unroll
      for (int n = 0; n < 4; ++n)
        bh[n] = *(const bf16x8*)&sBh[(wc*64 + n*16 + fr)*64 + ko*32 + fk*8];
      #pragma unroll
      for (int m = 0; m < 4; ++m)
        #pragma unroll
        for (int n = 0; n < 4; ++n)
          acc[m][n] = __builtin_amdgcn_mfma_f32_16x16x32_bf16(a[m], bh[n], acc[m][n], 0, 0, 0);
    }
    __syncthreads();
  }
  #pragma unroll
  for (int m = 0; m < 4; ++m) {
    #pragma unroll
    for (int n = 0; n < 4; ++n) {
      #pragma unroll
      for (int reg = 0; reg < 4; ++reg) {
        const int row = k0 + wr*64 + m*16 + (lane>>4)*4 + reg;
        const int col = c0 + wc*64 + n*16 + fr;
        INL[(size_t)row*N_HID + col] = acc[m][n][reg];
      }
    }
  }
}

// ---------------- phase A2: saturated-step precompute, fully parallel over k ----------------
__global__ __launch_bounds__(256) void k_sat(const float* __restrict__ INL,
                                             const float* __restrict__ Srow,
                                             float* __restrict__ HT,
                                             unsigned char* __restrict__ hsb8,
                                             unsigned short* __restrict__ ct16,
                                             unsigned char* __restrict__ statS,
                                             unsigned char* __restrict__ hzf) {
  const int w = threadIdx.x >> 6, lane = threadIdx.x & 63;
  const size_t k = (size_t)blockIdx.x*4 + w;
  const float4 srwa = *(const float4*)(Srow + lane*8);
  const float4 srwb = *(const float4*)(Srow + lane*8 + 4);
  const float4 cva = *(const float4*)(INL + k*N_HID + lane*8);
  const float4 cvb = *(const float4*)(INL + k*N_HID + lane*8 + 4);
  float nhm[8];
  nhm[0]=cva.x+srwa.x; nhm[1]=cva.y+srwa.y; nhm[2]=cva.z+srwa.z; nhm[3]=cva.w+srwa.w;
  nhm[4]=cvb.x+srwb.x; nhm[5]=cvb.y+srwb.y; nhm[6]=cvb.z+srwb.z; nhm[7]=cvb.w+srwb.w;
  int nhs[8];
  unsigned long long m[8];
  int ctot = 0;
  #pragma unroll
  for (int j = 0; j < 8; ++j) { nhs[j] = (nhm[j] >= THR) ? 1 : 0; m[j] = __ballot(nhs[j] != 0); }
  #pragma unroll
  for (int j = 0; j < 8; ++j) ctot += (int)__popcll(m[j]);
  unsigned int byte = 0;
  #pragma unroll
  for (int j = 0; j < 8; ++j) byte |= ((unsigned int)nhs[j]) << j;
  hsb8[k*64 + lane] = (unsigned char)byte;
  float ht[8];
  int hnz = 0;
  #pragma unroll
  for (int j = 0; j < 8; ++j) {
    const float a = fabsf(nhm[j] - THR) / THR;
    ht[j] = GAM * fmaxf(0.f, 1.f - a);
    hnz |= (ht[j] != 0.f);
  }
  const unsigned long long hb = __ballot(hnz != 0);
  if (hb != 0ULL) {
    *(float4*)(HT + k*N_HID + lane*8)     = make_float4(ht[0], ht[1], ht[2], ht[3]);
    *(float4*)(HT + k*N_HID + lane*8 + 4) = make_float4(ht[4], ht[5], ht[6], ht[7]);
  }
  if (lane == 0) {
    ct16[k]  = (unsigned short)ctot;
    statS[k] = (unsigned char)(((ctot == 512) ? 1u : 0u) | ((hb != 0ULL) ? 2u : 0u));
    hzf[k]   = (hb != 0ULL) ? 1 : 0;
  }
}

// ================= phase B: state-machine wave scan — LOAD-FREE table mode =================
__global__ __launch_bounds__(64, 1) void k_scan_tab(
    const float* __restrict__ INL, float* __restrict__ HT,
    const float* __restrict__ WoT, const float* __restrict__ WRT,
    const float* __restrict__ Srow, const float* __restrict__ SOs,
    unsigned char* __restrict__ hsb8, unsigned short* __restrict__ ctot16,
    float* __restrict__ drvb, unsigned char* __restrict__ hzf,
    const unsigned char* __restrict__ statS, int* __restrict__ tmaxp)
{
  __shared__ int list[N_HID];
  const int b = blockIdx.x, lane = threadIdx.x;
  const size_t base = (size_t)b*TT;
  const float4 srwa = *(const float4*)(Srow + lane*8);
  const float4 srwb = *(const float4*)(Srow + lane*8 + 4);
  float srw[8];
  srw[0]=srwa.x; srw[1]=srwa.y; srw[2]=srwa.z; srw[3]=srwa.w;
  srw[4]=srwb.x; srw[5]=srwb.y; srw[6]=srwb.z; srw[7]=srwb.w;
  float hm[8];
  int hs[8];
  #pragma unroll
  for (int j = 0; j < 8; ++j) { hm[j] = 0.f; hs[j] = 0; }
  const float SOsl = (lane < N_OUT) ? SOs[lane] : 0.f;
  int state = 0, cnt_prev = 0, mode_prev = 0, lastt = -1;

  auto GSTEP = [&](int t, unsigned st) {
    const size_t k = base + t;
    if (state == 1) {
      if (st & 1u) {
        if (st & 2u) lastt = t;
        return;
      }
      if (st & 2u) lastt = t;
      const float4 cva = *(const float4*)(INL + k*N_HID + lane*8);
      const float4 cvb = *(const float4*)(INL + k*N_HID + lane*8 + 4);
      const unsigned byte = hsb8[k*64 + lane];
      float cvv[8];
      cvv[0]=cva.x; cvv[1]=cva.y; cvv[2]=cva.z; cvv[3]=cva.w;
      cvv[4]=cvb.x; cvv[5]=cvb.y; cvv[6]=cvb.z; cvv[7]=cvb.w;
      int nhs[8];
      unsigned long long m[8];
      #pragma unroll
      for (int j = 0; j < 8; ++j) {
        hm[j] = cvv[j] + srw[j];
        nhs[j] = (int)((byte >> j) & 1u);
        m[j] = __ballot(nhs[j] != 0);
      }
      int ctot = 0;
      #pragma unroll
      for (int j = 0; j < 8; ++j) ctot += (int)__popcll(m[j]);
      const int mode = (ctot <= 256) ? 0 : 1;
      const int cnt  = mode ? (512 - ctot) : ctot;
      if (cnt != 0) {
        const unsigned long long below = (1ULL << lane) - 1ULL;
        int pos = 0;
        #pragma unroll
        for (int qq = 0; qq < 8; ++qq) {
          const unsigned long long sm = mode ? ~m[qq] : m[qq];
          pos += (int)__popcll(sm & below);
        }
        #pragma unroll
        for (int j = 0; j < 8; ++j) {
          const int sel = mode ? !nhs[j] : nhs[j];
          if (sel) list[pos++] = lane*8 + j;
        }
        float cdr = 0.f;
        for (int it = 0; it < cnt; ++it) {
          const int jj = list[it];
          cdr += (lane < N_OUT) ? WoT[jj*N_OUT + lane] : 0.f;
        }
        const float drv = mode ? (SOsl - cdr) : cdr;
        if (lane < N_OUT) drvb[k*N_OUT + lane] = drv;
      }
      #pragma unroll
      for (int j = 0; j < 8; ++j) hs[j] = nhs[j];
      cnt_prev = cnt; mode_prev = mode; state = 0;
      return;
    }
    // ---- SERIAL step ----
    const float4 cva = *(const float4*)(INL + k*N_HID + lane*8);
    const float4 cvb = *(const float4*)(INL + k*N_HID + lane*8 + 4);
    float rec[8];
    if (cnt_prev == 0 && mode_prev == 1) {
      #pragma unroll
      for (int j = 0; j < 8; ++j) rec[j] = srw[j];
    } else if (cnt_prev == 0) {
      #pragma unroll
      for (int j = 0; j < 8; ++j) rec[j] = 0.f;
    } else {
      float racc[8];
      #pragma unroll
      for (int j = 0; j < 8; ++j) racc[j] = 0.f;
      for (int it = 0; it < cnt_prev; ++it) {
        const int jj = list[it];
        const float4 wa = *(const float4*)(WRT + jj*N_HID + lane*8);
        const float4 wb = *(const float4*)(WRT + jj*N_HID + lane*8 + 4);
        racc[0]+=wa.x; racc[1]+=wa.y; racc[2]+=wa.z; racc[3]+=wa.w;
        racc[4]+=wb.x; racc[5]+=wb.y; racc[6]+=wb.z; racc[7]+=wb.w;
      }
      if (mode_prev) {
        #pragma unroll
        for (int j = 0; j < 8; ++j) rec[j] = srw[j] - racc[j];
      } else {
        #pragma unroll
        for (int j = 0; j < 8; ++j) rec[j] = racc[j];
      }
    }

    float cvv[8];
    cvv[0]=cva.x; cvv[1]=cva.y; cvv[2]=cva.z; cvv[3]=cva.w;
    cvv[4]=cvb.x; cvv[5]=cvb.y; cvv[6]=cvb.z; cvv[7]=cvb.w;
    float nhm[8]; int nhs[8];
    #pragma unroll
    for (int j = 0; j < 8; ++j)
      nhm[j] = TAU*hm[j]*(hs[j] ? 0.f : 1.f) + cvv[j] + rec[j];

    unsigned long long m[8];
    #pragma unroll
    for (int j = 0; j < 8; ++j) { nhs[j] = (nhm[j] >= THR) ? 1 : 0; m[j] = __ballot(nhs[j] != 0); }
    int ctot = 0;
    #pragma unroll
    for (int j = 0; j < 8; ++j) ctot += (int)__popcll(m[j]);
    {
      unsigned int byte = 0;
      #pragma unroll
      for (int j = 0; j < 8; ++j) byte |= ((unsigned int)nhs[j]) << j;
      hsb8[k*64 + lane] = (unsigned char)byte;
    }
    if (lane == 0) ctot16[k] = (unsigned short)ctot;
    const int mode = (ctot <= 256) ? 0 : 1;
    const int cnt  = mode ? (512 - ctot) : ctot;

    if (cnt != 0) {
      const unsigned long long below = (1ULL << lane) - 1ULL;
      int pos = 0;
      #pragma unroll
      for (int qq = 0; qq < 8; ++qq) {
        const unsigned long long sm = mode ? ~m[qq] : m[qq];
        pos += (int)__popcll(sm & below);
      }
      #pragma unroll
      for (int j = 0; j < 8; ++j) {
        const int sel = mode ? !nhs[j] : nhs[j];
        if (sel) list[pos++] = lane*8 + j;
      }
      float cdr = 0.f;
      for (int it = 0; it < cnt; ++it) {
        const int jj = list[it];
        cdr += (lane < N_OUT) ? WoT[jj*N_OUT + lane] : 0.f;
      }
      const float drv = mode ? (SOsl - cdr) : cdr;
      if (lane < N_OUT) drvb[k*N_OUT + lane] = drv;
    }

    float ht[8];
    int hnz = 0;
    #pragma unroll
    for (int j = 0; j < 8; ++j) {
      const float a = fabsf(nhm[j] - THR) / THR;
      ht[j] = GAM * fmaxf(0.f, 1.f - a);
      hnz |= (ht[j] != 0.f);
      hm[j] = nhm[j]; hs[j] = nhs[j];
    }
    const unsigned long long hb = __ballot(hnz != 0);
    if (hb != 0ULL) {
      *(float4*)(HT + k*N_HID + lane*8)     = make_float4(ht[0], ht[1], ht[2], ht[3]);
      *(float4*)(HT + k*N_HID + lane*8 + 4) = make_float4(ht[4], ht[5], ht[6], ht[7]);
      lastt = t;
    }
    if (lane == 0) hzf[k] = (hb != 0ULL) ? 1 : 0;
    cnt_prev = cnt; mode_prev = mode;
    state = (ctot == 512) ? 1 : 0;
  };

  uint32_t sv_cur  = *(const uint32_t*)(statS + base);
  uint32_t sv_next = *(const uint32_t*)(statS + base + 4);
  for (int tt = 0; tt < TT; tt += 4) {
    const uint32_t sv = sv_cur;
    {
      const int nn = (tt + 8 <= TT - 4) ? (tt + 8) : (TT - 4);
      sv_cur = sv_next;
      sv_next = *(const uint32_t*)(statS + base + nn);
    }
    if (state == 1 && (sv & 0x01010101u) == 0x01010101u) {
      if (sv & 0x02020202u) {
        if (sv & 0x02000000u)      lastt = tt + 3;
        else if (sv & 0x020000u)   lastt = tt + 2;
        else if (sv & 0x0200u)     lastt = tt + 1;
        else                       lastt = tt;
      }
      continue;
    }
    GSTEP(tt + 0, sv & 0xffu);
    GSTEP(tt + 1, (sv >> 8) & 0xffu);
    GSTEP(tt + 2, (sv >> 16) & 0xffu);
    GSTEP(tt + 3, (sv >> 24) & 0xffu);
  }
  if (lane == 0) tmaxp[b] = lastt + 1;
}

// ---------------- phase B2: output-neuron replay ----------------
__global__ __launch_bounds__(256) void k_out(const unsigned short* __restrict__ ct16,
                                             const float* __restrict__ drvb,
                                             const float* __restrict__ label,
                                             const float* __restrict__ SOs,
                                             float* __restrict__ outs,
                                             float* __restrict__ errb) {
  const int g = blockIdx.x*256 + threadIdx.x;
  if (g >= BB*N_OUT) return;
  const int b = g / N_OUT, o = g - b*N_OUT;
  const size_t base = (size_t)b*TT;
  const float SOso = SOs[o];
  int ctb[4]; float dvb[4], lab[4];
  #pragma unroll
  for (int q = 0; q < 4; ++q) {
    ctb[q] = ct16[base + q];
    dvb[q] = drvb[(base + q)*N_OUT + o];
    lab[q] = label[(base + q)*N_OUT + o];
  }
  float om = 0.f; int osb = 0;
  for (int tt = 0; tt < TT; tt += 4) {
    #pragma unroll
    for (int q = 0; q < 4; ++q) {
      const int t = tt + q;
      const size_t k = base + t;
      const int   ct = ctb[q];
      const float dv = dvb[q];
      const float la = lab[q];
      const size_t kp = (t + 4 < TT) ? (k + 4) : (base + TT - 1);
      ctb[q] = ct16[kp];
      dvb[q] = drvb[kp*N_OUT + o];
      lab[q] = label[kp*N_OUT + o];
      const int mode = (ct <= 256) ? 0 : 1;
      const int cnt  = mode ? (512 - ct) : ct;
      const float drv = (cnt != 0) ? dv : (mode ? SOso : 0.f);
      om = TAU*om*(osb ? 0.f : 1.f) + drv;
      const int nos = (om >= THR) ? 1 : 0;
      const float osf = nos ? 1.f : 0.f;
      outs[k*N_OUT + o] = osf;
      errb[k*N_OUT + o] = osf - la;
      osb = nos;
    }
  }
}

// ---------------- phase C1: go accumulation — single-wave blocks, r-split x8 ----------------
// grid BB*8 x 64 threads: hsbits word is wave-uniform (scalar load); 8 blocks/CU TLP.
// Per-(o,r) add order (t descending, spike-gated) identical to r21 -> bit-identical pgo.
__global__ __launch_bounds__(64, 1) void k_goacc(const float* __restrict__ errb,
                                                 const unsigned long long* __restrict__ hsbits,
                                                 float* __restrict__ pgo) {
  __shared__ __align__(16) float sE[TT][N_OUT];
  __shared__ __align__(16) float sF[TT][N_OUT];
  const int b = blockIdx.x >> 3;
  const int rblk = blockIdx.x & 7;
  const int lane = threadIdx.x;
  const int r = rblk*64 + lane;
  const size_t rb = (size_t)b*TT;

  for (int idx = lane; idx < TT*N_OUT; idx += 64)
    (&sE[0][0])[idx] = errb[rb*N_OUT + idx];
  __syncthreads();
  if (lane < N_OUT) {
    const int o = lane;
    float f = 0.f;
    for (int t = TT - 1; t >= 0; --t) {
      f = sE[t][o] + TAU_O*f;
      sF[t][o] = f;
    }
  }
  float goacc[N_OUT];
  #pragma unroll
  for (int o = 0; o < N_OUT; ++o) goacc[o] = 0.f;
  __syncthreads();

  unsigned long long word = hsbits[(rb + TT - 1)*8 + rblk];
  for (int t = TT - 1; t >= 0; --t) {
    const unsigned long long word_n = (t > 0) ? hsbits[(rb + t - 1)*8 + rblk] : 0ULL;
    if ((word >> lane) & 1ULL) {
      #pragma unroll
      for (int q = 0; q < 5; ++q) {
        const float4 f4 = *(const float4*)&sF[t][4*q];
        goacc[4*q+0] += f4.x; goacc[4*q+1] += f4.y; goacc[4*q+2] += f4.z; goacc[4*q+3] += f4.w;
      }
    }
    word = word_n;
  }
  #pragma unroll
  for (int o = 0; o < N_OUT; ++o)
    pgo[((size_t)b*N_OUT + o)*N_HID + r] = goacc[o];
}

// ---------------- phase C2: M for t < tmax only ----------------
__global__ __launch_bounds__(256, 1) void k_mshort(float* __restrict__ INL,
                                                   const float* __restrict__ HT,
                                                   const float* __restrict__ errb,
                                                   const unsigned char* __restrict__ hzf,
                                                   const float* __restrict__ Wo,
                                                   const int* __restrict__ tmax) {
  const int b = blockIdx.x >> 1;
  const int tm = tmax[b];
  if (tm == 0) return;
  const int r = (blockIdx.x & 1)*256 + threadIdx.x;
  const size_t rb = (size_t)b*TT;
  __shared__ __align__(16) float sE[TT][N_OUT];
  for (int idx = threadIdx.x; idx < tm*N_OUT; idx += 256)
    (&sE[0][0])[idx] = errb[rb*N_OUT + idx];
  __syncthreads();
  float woc[N_OUT];
  #pragma unroll
  for (int o = 0; o < N_OUT; ++o) woc[o] = Wo[o*N_HID + r];
  float mval = 0.f;
  for (int t = tm - 1; t >= 0; --t) {
    float d = 0.f;
    #pragma unroll
    for (int o = 0; o < N_OUT; ++o) d += sE[t][o] * woc[o];
    const float hp = hzf[rb + t] ? HT[(rb + t)*N_HID + r] : 0.f;
    const float v = d*hp + TAU*mval;
    INL[(rb + t)*N_HID + r] = v;
    mval = v;
  }
}

// ---------------- phase D: go reduce ----------------
__global__ __launch_bounds__(256) void k_go(const float* __restrict__ pgo, float* __restrict__ go) {
  __shared__ float red[4][64];
  const int l = threadIdx.x & 63;
  const int ch = threadIdx.x >> 6;
  const int col = blockIdx.x*64 + l;
  float s = 0.f;
  for (int b2 = ch*64; b2 < ch*64 + 64; ++b2)
    s += pgo[(size_t)b2*(N_OUT*N_HID) + col];
  red[ch][l] = s;
  __syncthreads();
  if (ch == 0) go[col] = 0.1f*(((red[0][l] + red[1][l]) + red[2][l]) + red[3][l]);
}

// ---------------- phase D: gf partials ----------------
__global__ __launch_bounds__(256) void k_gf(const float* __restrict__ M, const float* __restrict__ x,
                                            const int* __restrict__ tmax,
                                            float* __restrict__ gfp) {
  const int lane = threadIdx.x & 63, w = threadIdx.x >> 6;
  const int r  = blockIdx.x*64 + lane;
  const int i0 = blockIdx.y*64 + w*16;
  const int ch = blockIdx.z;
  const int b_lo = ch * (BB/NCH);
  __shared__ int cnt_sh[BB/NCH];
  if (threadIdx.x < BB/NCH) cnt_sh[threadIdx.x] = tmax[b_lo + threadIdx.x];
  __syncthreads();
  float acc[16];
  #pragma unroll
  for (int ii = 0; ii < 16; ++ii) acc[ii] = 0.f;
  int xi = i0 + (lane & 15); if (xi > N_IN - 1) xi = N_IN - 1;
  for (int bi = 0; bi < BB/NCH; ++bi) {
    const int ct = cnt_sh[bi];
    if (ct == 0) continue;
    const size_t kb = (size_t)(b_lo + bi)*TT;
    float mv = M[kb*N_HID + r];
    float xv = x[kb*N_IN + xi];
    for (int t = 0; t < ct; ++t) {
      float mv_n = 0.f, xv_n = 0.f;
      if (t + 1 < ct) {
        mv_n = M[(kb + t + 1)*N_HID + r];
        xv_n = x[(kb + t + 1)*N_IN + xi];
      }
      #pragma unroll
      for (int ii = 0; ii < 16; ++ii) acc[ii] += mv * __shfl(xv, ii);
      mv = mv_n; xv = xv_n;
    }
  }
  #pragma unroll
  for (int ii = 0; ii < 16; ++ii) {
    const int i = i0 + ii;
    if (i < N_IN) gfp[(size_t)ch*(N_HID*N_IN) + (size_t)r*N_IN + i] = acc[ii];
  }
}

// ---------------- phase D: gr partials ----------------
__global__ __launch_bounds__(256) void k_gr(const float* __restrict__ M,
                                            const unsigned long long* __restrict__ hsbits,
                                            const int* __restrict__ tmax,
                                            float* __restrict__ grp) {
  const int lane = threadIdx.x & 63, w = threadIdx.x >> 6;
  const int r  = blockIdx.x*64 + lane;
  const int h0 = blockIdx.y*64 + w*16;
  const int ch = blockIdx.z;
  const int b_lo = ch * (BB/NCH);
  __shared__ int cnt_sh[BB/NCH];
  if (threadIdx.x < BB/NCH) cnt_sh[threadIdx.x] = tmax[b_lo + threadIdx.x];
  __syncthreads();
  float acc[16];
  #pragma unroll
  for (int ii = 0; ii < 16; ++ii) acc[ii] = 0.f;
  const int hw = h0 >> 6, sh = h0 & 63;
  for (int bi = 0; bi < BB/NCH; ++bi) {
    const int ct = cnt_sh[bi];
    if (ct == 0) continue;
    const size_t kb = (size_t)(b_lo + bi)*TT;
    float mv = M[kb*N_HID + r];
    unsigned long long word = hsbits[kb*8 + hw];
    for (int t = 0; t < ct; ++t) {
      float mv_n = 0.f; unsigned long long word_n = 0ULL;
      if (t + 1 < ct) {
        mv_n = M[(kb + t + 1)*N_HID + r];
        word_n = hsbits[(kb + t + 1)*8 + hw];
      }
      #pragma unroll
      for (int ii = 0; ii < 16; ++ii)
        if ((word >> (sh + ii)) & 1ULL) acc[ii] += mv;
      mv = mv_n; word = word_n;
    }
  }
  #pragma unroll
  for (int ii = 0; ii < 16; ++ii)
    grp[(size_t)ch*(N_HID*N_HID) + (size_t)r*N_HID + h0 + ii] = acc[ii];
}

// ---------------- phase D: merged deterministic partial reductions ----------------
__global__ void k_redall(const float* __restrict__ gfp, const float* __restrict__ grp,
                         float* __restrict__ gf, float* __restrict__ gr) {
  const int g = blockIdx.x*256 + threadIdx.x;
  if (g < N_HID*N_IN) {
    float s = 0.f;
    #pragma unroll
    for (int c = 0; c < NCH; ++c) s += gfp[(size_t)c*(N_HID*N_IN) + g];
    gf[g] = 0.1f*s;
  } else if (g < N_HID*N_IN + N_HID*N_HID) {
    const int g2 = g - N_HID*N_IN;
    float s = 0.f;
    #pragma unroll
    for (int c = 0; c < NCH; ++c) s += grp[(size_t)c*(N_HID*N_HID) + g2];
    gr[g2] = 0.1f*s;
  }
}

extern "C" void kernel_launch(void* const* d_in, const int* in_sizes, int n_in,
                              void* d_out, int out_size, void* d_ws, size_t ws_size,
                              hipStream_t stream) {
  const float* x     = (const float*)d_in[0];
  const float* label = (const float*)d_in[1];
  const float* W1    = (const float*)d_in[2];
  const float* Wr    = (const float*)d_in[3];
  const float* Wo    = (const float*)d_in[4];

  float* out  = (float*)d_out;
  float* outs = out;
  float* gf   = out + 512000;
  float* gr   = out + 512000 + 358400;
  float* go   = out + 512000 + 358400 + 262144;

  char* ws = (char*)d_ws;
  size_t off = 0;
  auto alloc = [&](size_t bytes) -> char* {
    char* p = ws + off;
    off += (bytes + 255) & ~(size_t)255;
    return p;
  };
  float* INL = (float*)alloc((size_t)NK*N_HID*sizeof(float));                    // 52.43 MB
  unsigned long long* hsb = (unsigned long long*)alloc((size_t)NK*8*sizeof(unsigned long long)); // 1.64 MB
  int* tmax = (int*)alloc((size_t)BB*sizeof(int));
  char* uni = alloc((size_t)20971520);                                           // 20 MB union region

  unsigned short* WH = (unsigned short*)(uni);
  float* WRT  = (float*)(uni + 1441792);
  float* Srow = (float*)(uni + 2490368);
  float* SOs  = (float*)(uni + 2492416);
  float* WoT  = (float*)(uni + 2494464);
  float* errb = (float*)(uni + 2536448);
  float* pgo  = (float*)(uni + 4587520);
  float* drvb = (float*)(uni + 15073280);
  unsigned short* ct16 = (unsigned short*)(uni + 17121280);
  unsigned char* hzf   = (unsigned char*)(uni + 17172480);   // 25600 B
  unsigned char* statS = (unsigned char*)(uni + 17198336);   // 25600 B
  // late residents:
  float* gfp  = (float*)(uni);
  float* grp  = (float*)(uni + 11468800);

  float* HT = (float*)alloc((size_t)NK*N_HID*sizeof(float));  // 52.43 MB (fits: r21 passed)

  k_prep_all<<<(NK*N_OUT + 255)/256, 256, 0, stream>>>(W1, Wr, Wo, WH, WRT, WoT, Srow, SOs, drvb, hzf);
  dim3 gg(NK/128, N_HID/128);
  k_gemm<<<gg, 256, 0, stream>>>(x, WH, INL);
  k_sat<<<NK/4, 256, 0, stream>>>(INL, Srow, HT, (unsigned char*)hsb, ct16, statS, hzf);
  k_scan_tab<<<BB, 64, 0, stream>>>(INL, HT, WoT, WRT, Srow, SOs, (unsigned char*)hsb, ct16, drvb, hzf, statS, tmax);
  k_out<<<(BB*N_OUT + 255)/256, 256, 0, stream>>>(ct16, drvb, label, SOs, outs, errb);
  k_goacc<<<BB*8, 64, 0, stream>>>(errb, hsb, pgo);
  k_mshort<<<BB*2, 256, 0, stream>>>(INL, HT, errb, hzf, Wo, tmax);
  k_go<<<(N_OUT*N_HID)/64, 256, 0, stream>>>(pgo, go);
  dim3 ggf(8, 11, NCH); k_gf<<<ggf, 256, 0, stream>>>(INL, x, tmax, gfp);
  dim3 ggr(8, 8, NCH);  k_gr<<<ggr, 256, 0, stream>>>(INL, hsb, tmax, grp);
  k_redall<<<(N_HID*N_IN + N_HID*N_HID + 255)/256, 256, 0, stream>>>(gfp, grp, gf, gr);
}

// Round 23
// 278.022 us; speedup vs baseline: 1.0463x; 1.0463x over previous
//
#include <hip/hip_runtime.h>
#include <cstdint>
#include <cstddef>

#define N_IN  700
#define N_INP 704
#define N_HID 512
#define N_OUT 20
#define BB    256
#define TT    100
#define NK    (BB*TT)
#define NCH   8
#define LDA   32

__device__ __constant__ const float TAU   = 0.6f;
__device__ __constant__ const float TAU_O = 0.6f;
__device__ __constant__ const float THR   = 0.6f;
__device__ __constant__ const float GAM   = 0.3f;

typedef float f32x4 __attribute__((ext_vector_type(4)));
typedef __bf16 bf16x8 __attribute__((ext_vector_type(8)));

__device__ __forceinline__ unsigned short f2bf_rne(float f) {
  uint32_t b = __builtin_bit_cast(uint32_t, f);
  uint32_t r = (b + 0x7FFFu + ((b >> 16) & 1u)) >> 16;
  return (unsigned short)r;
}

// ---------------- merged prep: wsplit(hi only) + transposes + sums + zero-init ----------------
// NOTE: summation order of Srow/SOs is spike-determining — keep serial order exactly.
__global__ void k_prep_all(const float* __restrict__ W1, const float* __restrict__ Wr,
                           const float* __restrict__ Wo,
                           unsigned short* __restrict__ WH,
                           float* __restrict__ WRT, float* __restrict__ WoT,
                           float* __restrict__ Srow, float* __restrict__ SOs,
                           float* __restrict__ drvb, unsigned char* __restrict__ hzf) {
  const int g = blockIdx.x*256 + threadIdx.x;
  if (g < N_HID*88) {
    int r = g / 88, c = g - (g/88)*88;
    int ib = c*8;
    unsigned short h[8];
    #pragma unroll
    for (int j = 0; j < 8; ++j) {
      int i = ib + j;
      float v = (i < N_IN) ? W1[r*N_IN + i] : 0.f;
      h[j] = f2bf_rne(v);
    }
    uint4 hv = make_uint4((uint32_t)h[0] | ((uint32_t)h[1]<<16), (uint32_t)h[2] | ((uint32_t)h[3]<<16),
                          (uint32_t)h[4] | ((uint32_t)h[5]<<16), (uint32_t)h[6] | ((uint32_t)h[7]<<16));
    *(uint4*)(WH + (size_t)r*N_INP + ib) = hv;
  }
  if (g < N_HID*N_HID) {
    int j = g >> 9, r = g & 511;
    WRT[g] = Wr[r*N_HID + j];
  }
  if (g < N_HID*N_OUT) {
    int r = g / N_OUT, o = g - r*N_OUT;
    WoT[g] = Wo[o*N_HID + r];
  }
  if (g < N_HID) {
    float s = 0.f;
    for (int j = 0; j < N_HID; ++j) s += Wr[g*N_HID + j];
    Srow[g] = s;
  } else if (g < N_HID + N_OUT) {
    int o = g - N_HID;
    float s = 0.f;
    for (int r = 0; r < N_HID; ++r) s += Wo[o*N_HID + r];
    SOs[o] = s;
  }
  if (g < NK) hzf[g] = 0;
  if (g < NK*N_OUT) drvb[g] = 0.f;
}

// ---------------- phase A: INL = X @ WH^T, bf16 MFMA, 128x128, BK=32 (r21-proven best) ----------------
__global__ __launch_bounds__(256) void k_gemm(const float* __restrict__ x,
                                              const unsigned short* __restrict__ WH,
                                              float* __restrict__ INL) {
  __shared__ __align__(16) unsigned short sA [128*LDA];
  __shared__ __align__(16) unsigned short sBh[128*LDA];
  const int tid = threadIdx.x, lane = tid & 63, w = tid >> 6;
  const int k0 = blockIdx.x * 128;
  const int c0 = blockIdx.y * 128;
  const int wr = w >> 1, wc = w & 1;
  const int fr = lane & 15, fk = lane >> 4;

  const int a_r  = tid >> 1;
  const int a_cb = (tid & 1) * 16;
  const int b_r  = tid >> 2;
  const int b_c  = (tid & 3) * 8;

  const float* xr = x + (size_t)(k0 + a_r) * N_IN;
  const unsigned short* gh = WH + (size_t)(c0 + b_r) * N_INP;

  f32x4 acc[4][4];
  #pragma unroll
  for (int m = 0; m < 4; ++m)
    #pragma unroll
    for (int n = 0; n < 4; ++n)
      acc[m][n] = (f32x4){0.f, 0.f, 0.f, 0.f};

  for (int s = 0; s < N_INP/32; ++s) {
    const int i0 = s * 32;
    float av[16];
    const int col0 = i0 + a_cb;
    if (col0 + 16 <= N_IN) {
      float4 t0 = *(const float4*)(xr + col0);
      float4 t1 = *(const float4*)(xr + col0 + 4);
      float4 t2 = *(const float4*)(xr + col0 + 8);
      float4 t3 = *(const float4*)(xr + col0 + 12);
      av[0]=t0.x; av[1]=t0.y; av[2]=t0.z; av[3]=t0.w;
      av[4]=t1.x; av[5]=t1.y; av[6]=t1.z; av[7]=t1.w;
      av[8]=t2.x; av[9]=t2.y; av[10]=t2.z; av[11]=t2.w;
      av[12]=t3.x; av[13]=t3.y; av[14]=t3.z; av[15]=t3.w;
    } else {
      #pragma unroll
      for (int j = 0; j < 16; ++j) av[j] = (col0 + j < N_IN) ? xr[col0 + j] : 0.f;
    }
    uint32_t us[8];
    #pragma unroll
    for (int p = 0; p < 8; ++p) {
      uint32_t lo = __builtin_bit_cast(uint32_t, av[2*p])   >> 16;   // x in {0,1}: trunc exact
      uint32_t hi = __builtin_bit_cast(uint32_t, av[2*p+1]) & 0xFFFF0000u;
      us[p] = hi | lo;
    }
    *(uint4*)&sA[a_r*LDA + a_cb]     = make_uint4(us[0], us[1], us[2], us[3]);
    *(uint4*)&sA[a_r*LDA + a_cb + 8] = make_uint4(us[4], us[5], us[6], us[7]);
    *(uint4*)&sBh[b_r*LDA + b_c]      = *(const uint4*)(gh + i0 + b_c);
    *(uint4*)&sBh[(b_r+64)*LDA + b_c] = *(const uint4*)(gh + (size_t)64*N_INP + i0 + b_c);
    __syncthreads();

    bf16x8 a[4], bh[4];
    #pragma unroll
    for (int m = 0; m < 4; ++m)
      a[m] = *(const bf16x8*)&sA[(wr*64 + m*16 + fr)*LDA + fk*8];
    #pragma unroll
    for (int n = 0; n < 4; ++n)
      bh[n] = *(const bf16x8*)&sBh[(wc*64 + n*16 + fr)*LDA + fk*8];
    #pragma unroll
    for (int m = 0; m < 4; ++m)
      #pragma unroll
      for (int n = 0; n < 4; ++n)
        acc[m][n] = __builtin_amdgcn_mfma_f32_16x16x32_bf16(a[m], bh[n], acc[m][n], 0, 0, 0);
    __syncthreads();
  }
  #pragma unroll
  for (int m = 0; m < 4; ++m) {
    #pragma unroll
    for (int n = 0; n < 4; ++n) {
      #pragma unroll
      for (int reg = 0; reg < 4; ++reg) {
        const int row = k0 + wr*64 + m*16 + (lane>>4)*4 + reg;
        const int col = c0 + wc*64 + n*16 + fr;
        INL[(size_t)row*N_HID + col] = acc[m][n][reg];
      }
    }
  }
}

// ---------------- phase A2: saturated-step precompute, fully parallel over k ----------------
__global__ __launch_bounds__(256) void k_sat(const float* __restrict__ INL,
                                             const float* __restrict__ Srow,
                                             float* __restrict__ HT,
                                             unsigned char* __restrict__ hsb8,
                                             unsigned short* __restrict__ ct16,
                                             unsigned char* __restrict__ statS,
                                             unsigned char* __restrict__ hzf) {
  const int w = threadIdx.x >> 6, lane = threadIdx.x & 63;
  const size_t k = (size_t)blockIdx.x*4 + w;
  const float4 srwa = *(const float4*)(Srow + lane*8);
  const float4 srwb = *(const float4*)(Srow + lane*8 + 4);
  const float4 cva = *(const float4*)(INL + k*N_HID + lane*8);
  const float4 cvb = *(const float4*)(INL + k*N_HID + lane*8 + 4);
  float nhm[8];
  nhm[0]=cva.x+srwa.x; nhm[1]=cva.y+srwa.y; nhm[2]=cva.z+srwa.z; nhm[3]=cva.w+srwa.w;
  nhm[4]=cvb.x+srwb.x; nhm[5]=cvb.y+srwb.y; nhm[6]=cvb.z+srwb.z; nhm[7]=cvb.w+srwb.w;
  int nhs[8];
  unsigned long long m[8];
  int ctot = 0;
  #pragma unroll
  for (int j = 0; j < 8; ++j) { nhs[j] = (nhm[j] >= THR) ? 1 : 0; m[j] = __ballot(nhs[j] != 0); }
  #pragma unroll
  for (int j = 0; j < 8; ++j) ctot += (int)__popcll(m[j]);
  unsigned int byte = 0;
  #pragma unroll
  for (int j = 0; j < 8; ++j) byte |= ((unsigned int)nhs[j]) << j;
  hsb8[k*64 + lane] = (unsigned char)byte;
  float ht[8];
  int hnz = 0;
  #pragma unroll
  for (int j = 0; j < 8; ++j) {
    const float a = fabsf(nhm[j] - THR) / THR;
    ht[j] = GAM * fmaxf(0.f, 1.f - a);
    hnz |= (ht[j] != 0.f);
  }
  const unsigned long long hb = __ballot(hnz != 0);
  if (hb != 0ULL) {
    *(float4*)(HT + k*N_HID + lane*8)     = make_float4(ht[0], ht[1], ht[2], ht[3]);
    *(float4*)(HT + k*N_HID + lane*8 + 4) = make_float4(ht[4], ht[5], ht[6], ht[7]);
  }
  if (lane == 0) {
    ct16[k]  = (unsigned short)ctot;
    statS[k] = (unsigned char)(((ctot == 512) ? 1u : 0u) | ((hb != 0ULL) ? 2u : 0u));
    hzf[k]   = (hb != 0ULL) ? 1 : 0;
  }
}

// ================= phase B: state-machine wave scan — LOAD-FREE table mode =================
__global__ __launch_bounds__(64, 1) void k_scan_tab(
    const float* __restrict__ INL, float* __restrict__ HT,
    const float* __restrict__ WoT, const float* __restrict__ WRT,
    const float* __restrict__ Srow, const float* __restrict__ SOs,
    unsigned char* __restrict__ hsb8, unsigned short* __restrict__ ctot16,
    float* __restrict__ drvb, unsigned char* __restrict__ hzf,
    const unsigned char* __restrict__ statS, int* __restrict__ tmaxp)
{
  __shared__ int list[N_HID];
  const int b = blockIdx.x, lane = threadIdx.x;
  const size_t base = (size_t)b*TT;
  const float4 srwa = *(const float4*)(Srow + lane*8);
  const float4 srwb = *(const float4*)(Srow + lane*8 + 4);
  float srw[8];
  srw[0]=srwa.x; srw[1]=srwa.y; srw[2]=srwa.z; srw[3]=srwa.w;
  srw[4]=srwb.x; srw[5]=srwb.y; srw[6]=srwb.z; srw[7]=srwb.w;
  float hm[8];
  int hs[8];
  #pragma unroll
  for (int j = 0; j < 8; ++j) { hm[j] = 0.f; hs[j] = 0; }
  const float SOsl = (lane < N_OUT) ? SOs[lane] : 0.f;
  int state = 0, cnt_prev = 0, mode_prev = 0, lastt = -1;

  auto GSTEP = [&](int t, unsigned st) {
    const size_t k = base + t;
    if (state == 1) {
      if (st & 1u) {
        if (st & 2u) lastt = t;
        return;
      }
      if (st & 2u) lastt = t;
      const float4 cva = *(const float4*)(INL + k*N_HID + lane*8);
      const float4 cvb = *(const float4*)(INL + k*N_HID + lane*8 + 4);
      const unsigned byte = hsb8[k*64 + lane];
      float cvv[8];
      cvv[0]=cva.x; cvv[1]=cva.y; cvv[2]=cva.z; cvv[3]=cva.w;
      cvv[4]=cvb.x; cvv[5]=cvb.y; cvv[6]=cvb.z; cvv[7]=cvb.w;
      int nhs[8];
      unsigned long long m[8];
      #pragma unroll
      for (int j = 0; j < 8; ++j) {
        hm[j] = cvv[j] + srw[j];
        nhs[j] = (int)((byte >> j) & 1u);
        m[j] = __ballot(nhs[j] != 0);
      }
      int ctot = 0;
      #pragma unroll
      for (int j = 0; j < 8; ++j) ctot += (int)__popcll(m[j]);
      const int mode = (ctot <= 256) ? 0 : 1;
      const int cnt  = mode ? (512 - ctot) : ctot;
      if (cnt != 0) {
        const unsigned long long below = (1ULL << lane) - 1ULL;
        int pos = 0;
        #pragma unroll
        for (int qq = 0; qq < 8; ++qq) {
          const unsigned long long sm = mode ? ~m[qq] : m[qq];
          pos += (int)__popcll(sm & below);
        }
        #pragma unroll
        for (int j = 0; j < 8; ++j) {
          const int sel = mode ? !nhs[j] : nhs[j];
          if (sel) list[pos++] = lane*8 + j;
        }
        float cdr = 0.f;
        for (int it = 0; it < cnt; ++it) {
          const int jj = list[it];
          cdr += (lane < N_OUT) ? WoT[jj*N_OUT + lane] : 0.f;
        }
        const float drv = mode ? (SOsl - cdr) : cdr;
        if (lane < N_OUT) drvb[k*N_OUT + lane] = drv;
      }
      #pragma unroll
      for (int j = 0; j < 8; ++j) hs[j] = nhs[j];
      cnt_prev = cnt; mode_prev = mode; state = 0;
      return;
    }
    // ---- SERIAL step ----
    const float4 cva = *(const float4*)(INL + k*N_HID + lane*8);
    const float4 cvb = *(const float4*)(INL + k*N_HID + lane*8 + 4);
    float rec[8];
    if (cnt_prev == 0 && mode_prev == 1) {
      #pragma unroll
      for (int j = 0; j < 8; ++j) rec[j] = srw[j];
    } else if (cnt_prev == 0) {
      #pragma unroll
      for (int j = 0; j < 8; ++j) rec[j] = 0.f;
    } else {
      float racc[8];
      #pragma unroll
      for (int j = 0; j < 8; ++j) racc[j] = 0.f;
      for (int it = 0; it < cnt_prev; ++it) {
        const int jj = list[it];
        const float4 wa = *(const float4*)(WRT + jj*N_HID + lane*8);
        const float4 wb = *(const float4*)(WRT + jj*N_HID + lane*8 + 4);
        racc[0]+=wa.x; racc[1]+=wa.y; racc[2]+=wa.z; racc[3]+=wa.w;
        racc[4]+=wb.x; racc[5]+=wb.y; racc[6]+=wb.z; racc[7]+=wb.w;
      }
      if (mode_prev) {
        #pragma unroll
        for (int j = 0; j < 8; ++j) rec[j] = srw[j] - racc[j];
      } else {
        #pragma unroll
        for (int j = 0; j < 8; ++j) rec[j] = racc[j];
      }
    }

    float cvv[8];
    cvv[0]=cva.x; cvv[1]=cva.y; cvv[2]=cva.z; cvv[3]=cva.w;
    cvv[4]=cvb.x; cvv[5]=cvb.y; cvv[6]=cvb.z; cvv[7]=cvb.w;
    float nhm[8]; int nhs[8];
    #pragma unroll
    for (int j = 0; j < 8; ++j)
      nhm[j] = TAU*hm[j]*(hs[j] ? 0.f : 1.f) + cvv[j] + rec[j];

    unsigned long long m[8];
    #pragma unroll
    for (int j = 0; j < 8; ++j) { nhs[j] = (nhm[j] >= THR) ? 1 : 0; m[j] = __ballot(nhs[j] != 0); }
    int ctot = 0;
    #pragma unroll
    for (int j = 0; j < 8; ++j) ctot += (int)__popcll(m[j]);
    {
      unsigned int byte = 0;
      #pragma unroll
      for (int j = 0; j < 8; ++j) byte |= ((unsigned int)nhs[j]) << j;
      hsb8[k*64 + lane] = (unsigned char)byte;
    }
    if (lane == 0) ctot16[k] = (unsigned short)ctot;
    const int mode = (ctot <= 256) ? 0 : 1;
    const int cnt  = mode ? (512 - ctot) : ctot;

    if (cnt != 0) {
      const unsigned long long below = (1ULL << lane) - 1ULL;
      int pos = 0;
      #pragma unroll
      for (int qq = 0; qq < 8; ++qq) {
        const unsigned long long sm = mode ? ~m[qq] : m[qq];
        pos += (int)__popcll(sm & below);
      }
      #pragma unroll
      for (int j = 0; j < 8; ++j) {
        const int sel = mode ? !nhs[j] : nhs[j];
        if (sel) list[pos++] = lane*8 + j;
      }
      float cdr = 0.f;
      for (int it = 0; it < cnt; ++it) {
        const int jj = list[it];
        cdr += (lane < N_OUT) ? WoT[jj*N_OUT + lane] : 0.f;
      }
      const float drv = mode ? (SOsl - cdr) : cdr;
      if (lane < N_OUT) drvb[k*N_OUT + lane] = drv;
    }

    float ht[8];
    int hnz = 0;
    #pragma unroll
    for (int j = 0; j < 8; ++j) {
      const float a = fabsf(nhm[j] - THR) / THR;
      ht[j] = GAM * fmaxf(0.f, 1.f - a);
      hnz |= (ht[j] != 0.f);
      hm[j] = nhm[j]; hs[j] = nhs[j];
    }
    const unsigned long long hb = __ballot(hnz != 0);
    if (hb != 0ULL) {
      *(float4*)(HT + k*N_HID + lane*8)     = make_float4(ht[0], ht[1], ht[2], ht[3]);
      *(float4*)(HT + k*N_HID + lane*8 + 4) = make_float4(ht[4], ht[5], ht[6], ht[7]);
      lastt = t;
    }
    if (lane == 0) hzf[k] = (hb != 0ULL) ? 1 : 0;
    cnt_prev = cnt; mode_prev = mode;
    state = (ctot == 512) ? 1 : 0;
  };

  uint32_t sv_cur  = *(const uint32_t*)(statS + base);
  uint32_t sv_next = *(const uint32_t*)(statS + base + 4);
  for (int tt = 0; tt < TT; tt += 4) {
    const uint32_t sv = sv_cur;
    {
      const int nn = (tt + 8 <= TT - 4) ? (tt + 8) : (TT - 4);
      sv_cur = sv_next;
      sv_next = *(const uint32_t*)(statS + base + nn);
    }
    if (state == 1 && (sv & 0x01010101u) == 0x01010101u) {
      if (sv & 0x02020202u) {
        if (sv & 0x02000000u)      lastt = tt + 3;
        else if (sv & 0x020000u)   lastt = tt + 2;
        else if (sv & 0x0200u)     lastt = tt + 1;
        else                       lastt = tt;
      }
      continue;
    }
    GSTEP(tt + 0, sv & 0xffu);
    GSTEP(tt + 1, (sv >> 8) & 0xffu);
    GSTEP(tt + 2, (sv >> 16) & 0xffu);
    GSTEP(tt + 3, (sv >> 24) & 0xffu);
  }
  if (lane == 0) tmaxp[b] = lastt + 1;
}

// ---------------- phase B2: output-neuron replay ----------------
__global__ __launch_bounds__(256) void k_out(const unsigned short* __restrict__ ct16,
                                             const float* __restrict__ drvb,
                                             const float* __restrict__ label,
                                             const float* __restrict__ SOs,
                                             float* __restrict__ outs,
                                             float* __restrict__ errb) {
  const int g = blockIdx.x*256 + threadIdx.x;
  if (g >= BB*N_OUT) return;
  const int b = g / N_OUT, o = g - b*N_OUT;
  const size_t base = (size_t)b*TT;
  const float SOso = SOs[o];
  int ctb[4]; float dvb[4], lab[4];
  #pragma unroll
  for (int q = 0; q < 4; ++q) {
    ctb[q] = ct16[base + q];
    dvb[q] = drvb[(base + q)*N_OUT + o];
    lab[q] = label[(base + q)*N_OUT + o];
  }
  float om = 0.f; int osb = 0;
  for (int tt = 0; tt < TT; tt += 4) {
    #pragma unroll
    for (int q = 0; q < 4; ++q) {
      const int t = tt + q;
      const size_t k = base + t;
      const int   ct = ctb[q];
      const float dv = dvb[q];
      const float la = lab[q];
      const size_t kp = (t + 4 < TT) ? (k + 4) : (base + TT - 1);
      ctb[q] = ct16[kp];
      dvb[q] = drvb[kp*N_OUT + o];
      lab[q] = label[kp*N_OUT + o];
      const int mode = (ct <= 256) ? 0 : 1;
      const int cnt  = mode ? (512 - ct) : ct;
      const float drv = (cnt != 0) ? dv : (mode ? SOso : 0.f);
      om = TAU*om*(osb ? 0.f : 1.f) + drv;
      const int nos = (om >= THR) ? 1 : 0;
      const float osf = nos ? 1.f : 0.f;
      outs[k*N_OUT + o] = osf;
      errb[k*N_OUT + o] = osf - la;
      osb = nos;
    }
  }
}

// ---------------- phase C1: go accumulation — single-wave blocks, r-split x8 ----------------
__global__ __launch_bounds__(64, 1) void k_goacc(const float* __restrict__ errb,
                                                 const unsigned long long* __restrict__ hsbits,
                                                 float* __restrict__ pgo) {
  __shared__ __align__(16) float sE[TT][N_OUT];
  __shared__ __align__(16) float sF[TT][N_OUT];
  const int b = blockIdx.x >> 3;
  const int rblk = blockIdx.x & 7;
  const int lane = threadIdx.x;
  const int r = rblk*64 + lane;
  const size_t rb = (size_t)b*TT;

  for (int idx = lane; idx < TT*N_OUT; idx += 64)
    (&sE[0][0])[idx] = errb[rb*N_OUT + idx];
  __syncthreads();
  if (lane < N_OUT) {
    const int o = lane;
    float f = 0.f;
    for (int t = TT - 1; t >= 0; --t) {
      f = sE[t][o] + TAU_O*f;
      sF[t][o] = f;
    }
  }
  float goacc[N_OUT];
  #pragma unroll
  for (int o = 0; o < N_OUT; ++o) goacc[o] = 0.f;
  __syncthreads();

  unsigned long long word = hsbits[(rb + TT - 1)*8 + rblk];
  for (int t = TT - 1; t >= 0; --t) {
    const unsigned long long word_n = (t > 0) ? hsbits[(rb + t - 1)*8 + rblk] : 0ULL;
    if ((word >> lane) & 1ULL) {
      #pragma unroll
      for (int q = 0; q < 5; ++q) {
        const float4 f4 = *(const float4*)&sF[t][4*q];
        goacc[4*q+0] += f4.x; goacc[4*q+1] += f4.y; goacc[4*q+2] += f4.z; goacc[4*q+3] += f4.w;
      }
    }
    word = word_n;
  }
  #pragma unroll
  for (int o = 0; o < N_OUT; ++o)
    pgo[((size_t)b*N_OUT + o)*N_HID + r] = goacc[o];
}

// ---------------- phase C2: M for t < tmax only ----------------
__global__ __launch_bounds__(256, 1) void k_mshort(float* __restrict__ INL,
                                                   const float* __restrict__ HT,
                                                   const float* __restrict__ errb,
                                                   const unsigned char* __restrict__ hzf,
                                                   const float* __restrict__ Wo,
                                                   const int* __restrict__ tmax) {
  const int b = blockIdx.x >> 1;
  const int tm = tmax[b];
  if (tm == 0) return;
  const int r = (blockIdx.x & 1)*256 + threadIdx.x;
  const size_t rb = (size_t)b*TT;
  __shared__ __align__(16) float sE[TT][N_OUT];
  for (int idx = threadIdx.x; idx < tm*N_OUT; idx += 256)
    (&sE[0][0])[idx] = errb[rb*N_OUT + idx];
  __syncthreads();
  float woc[N_OUT];
  #pragma unroll
  for (int o = 0; o < N_OUT; ++o) woc[o] = Wo[o*N_HID + r];
  float mval = 0.f;
  for (int t = tm - 1; t >= 0; --t) {
    float d = 0.f;
    #pragma unroll
    for (int o = 0; o < N_OUT; ++o) d += sE[t][o] * woc[o];
    const float hp = hzf[rb + t] ? HT[(rb + t)*N_HID + r] : 0.f;
    const float v = d*hp + TAU*mval;
    INL[(rb + t)*N_HID + r] = v;
    mval = v;
  }
}

// ---------------- phase D: go reduce ----------------
__global__ __launch_bounds__(256) void k_go(const float* __restrict__ pgo, float* __restrict__ go) {
  __shared__ float red[4][64];
  const int l = threadIdx.x & 63;
  const int ch = threadIdx.x >> 6;
  const int col = blockIdx.x*64 + l;
  float s = 0.f;
  for (int b2 = ch*64; b2 < ch*64 + 64; ++b2)
    s += pgo[(size_t)b2*(N_OUT*N_HID) + col];
  red[ch][l] = s;
  __syncthreads();
  if (ch == 0) go[col] = 0.1f*(((red[0][l] + red[1][l]) + red[2][l]) + red[3][l]);
}

// ---------------- phase D: gf partials ----------------
__global__ __launch_bounds__(256) void k_gf(const float* __restrict__ M, const float* __restrict__ x,
                                            const int* __restrict__ tmax,
                                            float* __restrict__ gfp) {
  const int lane = threadIdx.x & 63, w = threadIdx.x >> 6;
  const int r  = blockIdx.x*64 + lane;
  const int i0 = blockIdx.y*64 + w*16;
  const int ch = blockIdx.z;
  const int b_lo = ch * (BB/NCH);
  __shared__ int cnt_sh[BB/NCH];
  if (threadIdx.x < BB/NCH) cnt_sh[threadIdx.x] = tmax[b_lo + threadIdx.x];
  __syncthreads();
  float acc[16];
  #pragma unroll
  for (int ii = 0; ii < 16; ++ii) acc[ii] = 0.f;
  int xi = i0 + (lane & 15); if (xi > N_IN - 1) xi = N_IN - 1;
  for (int bi = 0; bi < BB/NCH; ++bi) {
    const int ct = cnt_sh[bi];
    if (ct == 0) continue;
    const size_t kb = (size_t)(b_lo + bi)*TT;
    float mv = M[kb*N_HID + r];
    float xv = x[kb*N_IN + xi];
    for (int t = 0; t < ct; ++t) {
      float mv_n = 0.f, xv_n = 0.f;
      if (t + 1 < ct) {
        mv_n = M[(kb + t + 1)*N_HID + r];
        xv_n = x[(kb + t + 1)*N_IN + xi];
      }
      #pragma unroll
      for (int ii = 0; ii < 16; ++ii) acc[ii] += mv * __shfl(xv, ii);
      mv = mv_n; xv = xv_n;
    }
  }
  #pragma unroll
  for (int ii = 0; ii < 16; ++ii) {
    const int i = i0 + ii;
    if (i < N_IN) gfp[(size_t)ch*(N_HID*N_IN) + (size_t)r*N_IN + i] = acc[ii];
  }
}

// ---------------- phase D: gr partials ----------------
__global__ __launch_bounds__(256) void k_gr(const float* __restrict__ M,
                                            const unsigned long long* __restrict__ hsbits,
                                            const int* __restrict__ tmax,
                                            float* __restrict__ grp) {
  const int lane = threadIdx.x & 63, w = threadIdx.x >> 6;
  const int r  = blockIdx.x*64 + lane;
  const int h0 = blockIdx.y*64 + w*16;
  const int ch = blockIdx.z;
  const int b_lo = ch * (BB/NCH);
  __shared__ int cnt_sh[BB/NCH];
  if (threadIdx.x < BB/NCH) cnt_sh[threadIdx.x] = tmax[b_lo + threadIdx.x];
  __syncthreads();
  float acc[16];
  #pragma unroll
  for (int ii = 0; ii < 16; ++ii) acc[ii] = 0.f;
  const int hw = h0 >> 6, sh = h0 & 63;
  for (int bi = 0; bi < BB/NCH; ++bi) {
    const int ct = cnt_sh[bi];
    if (ct == 0) continue;
    const size_t kb = (size_t)(b_lo + bi)*TT;
    float mv = M[kb*N_HID + r];
    unsigned long long word = hsbits[kb*8 + hw];
    for (int t = 0; t < ct; ++t) {
      float mv_n = 0.f; unsigned long long word_n = 0ULL;
      if (t + 1 < ct) {
        mv_n = M[(kb + t + 1)*N_HID + r];
        word_n = hsbits[(kb + t + 1)*8 + hw];
      }
      #pragma unroll
      for (int ii = 0; ii < 16; ++ii)
        if ((word >> (sh + ii)) & 1ULL) acc[ii] += mv;
      mv = mv_n; word = word_n;
    }
  }
  #pragma unroll
  for (int ii = 0; ii < 16; ++ii)
    grp[(size_t)ch*(N_HID*N_HID) + (size_t)r*N_HID + h0 + ii] = acc[ii];
}

// ---------------- phase D: merged deterministic partial reductions ----------------
__global__ void k_redall(const float* __restrict__ gfp, const float* __restrict__ grp,
                         float* __restrict__ gf, float* __restrict__ gr) {
  const int g = blockIdx.x*256 + threadIdx.x;
  if (g < N_HID*N_IN) {
    float s = 0.f;
    #pragma unroll
    for (int c = 0; c < NCH; ++c) s += gfp[(size_t)c*(N_HID*N_IN) + g];
    gf[g] = 0.1f*s;
  } else if (g < N_HID*N_IN + N_HID*N_HID) {
    const int g2 = g - N_HID*N_IN;
    float s = 0.f;
    #pragma unroll
    for (int c = 0; c < NCH; ++c) s += grp[(size_t)c*(N_HID*N_HID) + g2];
    gr[g2] = 0.1f*s;
  }
}

extern "C" void kernel_launch(void* const* d_in, const int* in_sizes, int n_in,
                              void* d_out, int out_size, void* d_ws, size_t ws_size,
                              hipStream_t stream) {
  const float* x     = (const float*)d_in[0];
  const float* label = (const float*)d_in[1];
  const float* W1    = (const float*)d_in[2];
  const float* Wr    = (const float*)d_in[3];
  const float* Wo    = (const float*)d_in[4];

  float* out  = (float*)d_out;
  float* outs = out;
  float* gf   = out + 512000;
  float* gr   = out + 512000 + 358400;
  float* go   = out + 512000 + 358400 + 262144;

  char* ws = (char*)d_ws;
  size_t off = 0;
  auto alloc = [&](size_t bytes) -> char* {
    char* p = ws + off;
    off += (bytes + 255) & ~(size_t)255;
    return p;
  };
  float* INL = (float*)alloc((size_t)NK*N_HID*sizeof(float));                    // 52.43 MB
  unsigned long long* hsb = (unsigned long long*)alloc((size_t)NK*8*sizeof(unsigned long long)); // 1.64 MB
  int* tmax = (int*)alloc((size_t)BB*sizeof(int));
  char* uni = alloc((size_t)20971520);                                           // 20 MB union region

  unsigned short* WH = (unsigned short*)(uni);
  float* WRT  = (float*)(uni + 1441792);
  float* Srow = (float*)(uni + 2490368);
  float* SOs  = (float*)(uni + 2492416);
  float* WoT  = (float*)(uni + 2494464);
  float* errb = (float*)(uni + 2536448);
  float* pgo  = (float*)(uni + 4587520);
  float* drvb = (float*)(uni + 15073280);
  unsigned short* ct16 = (unsigned short*)(uni + 17121280);
  unsigned char* hzf   = (unsigned char*)(uni + 17172480);   // 25600 B
  unsigned char* statS = (unsigned char*)(uni + 17198336);   // 25600 B
  // late residents:
  float* gfp  = (float*)(uni);
  float* grp  = (float*)(uni + 11468800);

  float* HT = (float*)alloc((size_t)NK*N_HID*sizeof(float));  // 52.43 MB (fits: r21/r22 passed)

  k_prep_all<<<(NK*N_OUT + 255)/256, 256, 0, stream>>>(W1, Wr, Wo, WH, WRT, WoT, Srow, SOs, drvb, hzf);
  dim3 gg(NK/128, N_HID/128);
  k_gemm<<<gg, 256, 0, stream>>>(x, WH, INL);
  k_sat<<<NK/4, 256, 0, stream>>>(INL, Srow, HT, (unsigned char*)hsb, ct16, statS, hzf);
  k_scan_tab<<<BB, 64, 0, stream>>>(INL, HT, WoT, WRT, Srow, SOs, (unsigned char*)hsb, ct16, drvb, hzf, statS, tmax);
  k_out<<<(BB*N_OUT + 255)/256, 256, 0, stream>>>(ct16, drvb, label, SOs, outs, errb);
  k_goacc<<<BB*8, 64, 0, stream>>>(errb, hsb, pgo);
  k_mshort<<<BB*2, 256, 0, stream>>>(INL, HT, errb, hzf, Wo, tmax);
  k_go<<<(N_OUT*N_HID)/64, 256, 0, stream>>>(pgo, go);
  dim3 ggf(8, 11, NCH); k_gf<<<ggf, 256, 0, stream>>>(INL, x, tmax, gfp);
  dim3 ggr(8, 8, NCH);  k_gr<<<ggr, 256, 0, stream>>>(INL, hsb, tmax, grp);
  k_redall<<<(N_HID*N_IN + N_HID*N_HID + 255)/256, 256, 0, stream>>>(gfp, grp, gf, gr);
}